// Round 1
// baseline (2289.128 us; speedup 1.0000x reference)
//
#include <hip/hip_runtime.h>

#define HID 256
#define T_STEPS 1024
#define F_IN 40
#define NSPK 1251
#define NCHUNK 8            // workgroups per layer
#define NBLOCKS (3 * NCHUNK)
#define K2_THREADS 512

// workspace layout:
//   tagged h words: u64 hbuf[3][1025][256]   (tag = time index, low 32 = float bits)
//   plain float h2f[1024][256] for the logits GEMM
#define HBUF_WORDS (3 * 1025 * 256)
#define H2F_OFF_BYTES ((size_t)HBUF_WORDS * 8)

__device__ __forceinline__ float fast_sig(float v) {
    return __builtin_amdgcn_rcpf(1.f + __expf(-v));
}
__device__ __forceinline__ float fast_tanh(float v) {
    return 2.f * __builtin_amdgcn_rcpf(1.f + __expf(-2.f * v)) - 1.f;
}

// ---------------- K0: init h[l][0][:] = (tag 0 | 0.0f) ----------------
__global__ void k0_init(unsigned long long* __restrict__ hbuf) {
    int tid = threadIdx.x;
    if (tid < 3 * HID) {
        int l = tid / HID, k = tid % HID;
        hbuf[(size_t)(l * 1025 + 0) * HID + k] = 0ull;   // tag 0, value 0.0f
    }
}

// ---------------- K2: pipelined 3-layer LSTM, tagged-word sync ----------------
// Thread mapping (per block = one layer-chunk of 32 h-indices):
//   j   = tid >> 4        (0..31)  h-index within chunk; lane tid%16==0 is the update lane
//   q   = (tid >> 2) & 3  gate (i,f,g,o rows q*256 + g*32 + j)
//   seg = tid & 3         128-wide k-segment (0,1 = input/prev-layer; 2,3 = own h)
// All 4 gates of one j live in a single 16-lane group -> gate exchange via shfl_xor,
// no LDS gate buffer, no second barrier; each wave publishes right after its dot.
// LDS input vector is double-buffered -> exactly ONE __syncthreads per timestep.
__global__ __launch_bounds__(K2_THREADS) void k2_lstm(
    const float* __restrict__ x,
    const float* __restrict__ w_ih0, const float* __restrict__ w_hh0,
    const float* __restrict__ b_ih0, const float* __restrict__ b_hh0,
    const float* __restrict__ w_ih1, const float* __restrict__ w_hh1,
    const float* __restrict__ b_ih1, const float* __restrict__ b_hh1,
    const float* __restrict__ w_ih2, const float* __restrict__ w_hh2,
    const float* __restrict__ b_ih2, const float* __restrict__ b_hh2,
    unsigned long long* __restrict__ hbuf, float* __restrict__ h2f)
{
    const int bid = blockIdx.x;
    const int layer = bid / NCHUNK;      // 0..2
    const int g     = bid % NCHUNK;      // chunk of 32 h-indices
    const int tid   = threadIdx.x;
    const int seg = tid & 3;             // k-segment 0..3 (128 wide each)
    const int q   = (tid >> 2) & 3;      // gate 0..3 (i,f,g,o)
    const int j   = tid >> 4;            // 0..31 local h-index
    const int r   = q * 256 + g * 32 + j;  // global gate row 0..1023

    const float* wih = (layer == 0) ? w_ih0 : (layer == 1) ? w_ih1 : w_ih2;
    const float* whh = (layer == 0) ? w_hh0 : (layer == 1) ? w_hh1 : w_hh2;
    const float* bih = (layer == 0) ? b_ih0 : (layer == 1) ? b_ih1 : b_ih2;
    const float* bhh = (layer == 0) ? b_hh0 : (layer == 1) ? b_hh1 : b_hh2;

    // double-buffered input vector: buf[p][0:256] = input (x row / prev-layer h),
    //                               buf[p][256:512] = own h
    __shared__ float lds_sh[1024];

    // ---- load this thread's 128 weights into registers, pre-rotated by seg*8
    // floats so the LDS dot reads conflict-free (segs hit disjoint bank quads) ----
    float w[128];
    const int rot4 = 2 * seg;            // rotation in float4 units within the 32-float4 slice
    if (seg >= 2) {
        const float4* src = (const float4*)(whh + r * HID + (seg - 2) * 128);
        #pragma unroll
        for (int k4 = 0; k4 < 32; k4++) {
            float4 v = src[(k4 + rot4) & 31];
            w[k4 * 4 + 0] = v.x; w[k4 * 4 + 1] = v.y;
            w[k4 * 4 + 2] = v.z; w[k4 * 4 + 3] = v.w;
        }
    } else if (layer > 0) {
        const float4* src = (const float4*)(wih + r * HID + seg * 128);
        #pragma unroll
        for (int k4 = 0; k4 < 32; k4++) {
            float4 v = src[(k4 + rot4) & 31];
            w[k4 * 4 + 0] = v.x; w[k4 * 4 + 1] = v.y;
            w[k4 * 4 + 2] = v.z; w[k4 * 4 + 3] = v.w;
        }
    } else {
        // layer 0: seg0 holds the 40-wide x-projection row (rot=0), seg1 all-zero
        #pragma unroll
        for (int k = 0; k < 128; k++) w[k] = 0.f;
        if (seg == 0) {
            for (int k = 0; k < F_IN; k++) w[k] = w_ih0[r * F_IN + k];
        }
    }
    float bias = (seg == 0) ? (bih[r] + bhh[r]) : 0.f;

    for (int i = tid; i < 1024; i += K2_THREADS) lds_sh[i] = 0.f;
    __syncthreads();

    const float* x63 = x + 63 * T_STEPS * F_IN;
    const unsigned long long* h_prev_layer = hbuf + (size_t)(layer - 1) * 1025 * HID; // layer>0 only
    unsigned long long* h_own              = hbuf + (size_t)layer * 1025 * HID;

    float c_state = 0.f;   // valid on update lanes (tid%16==0)
    const bool is_upd = ((tid & 15) == 0);

    for (int t = 0; t < T_STEPS; t++) {
        float* buf  = lds_sh + ((t & 1) << 9);        // this step's input vector
        float* bufn = lds_sh + (((t + 1) & 1) << 9);  // next step's (written post-barrier only)

        // ---- gather this step's inputs into buf (writes ONLY buf: its previous
        // readers were dot(t-2), separated by the barrier of step t-1 -> no WAR) ----
        if (tid < 256) {
            const int k = tid;
            if ((k >> 5) != g) {
                // sibling chunks' h[t], expected tag = t (own chunk slot was
                // written into this buffer by our update lane at step t-1)
                const unsigned long long* p = h_own + (size_t)t * HID + k;
                unsigned long long v;
                do {
                    v = __hip_atomic_load(p, __ATOMIC_RELAXED, __HIP_MEMORY_SCOPE_AGENT);
                } while ((unsigned)(v >> 32) != (unsigned)t);
                buf[256 + k] = __uint_as_float((unsigned)v);
            }
        } else if (layer > 0) {
            // prev-layer h[t+1], expected tag = t+1
            const unsigned long long* p = h_prev_layer + (size_t)(t + 1) * HID + (tid - 256);
            unsigned long long v;
            do {
                v = __hip_atomic_load(p, __ATOMIC_RELAXED, __HIP_MEMORY_SCOPE_AGENT);
            } while ((unsigned)(v >> 32) != (unsigned)(t + 1));
            buf[tid - 256] = __uint_as_float((unsigned)v);
        } else if (tid < 256 + 10 && t == 0) {
            // layer 0, first step only: stage x[63][0][:]; later steps are prefetched
            ((float4*)buf)[tid - 256] = ((const float4*)(x63))[tid - 256];
        }
        __syncthreads();   // the ONLY barrier per step

        // layer 0: prefetch next x row into bufn (legal only after the barrier:
        // all dot(t-1) readers of bufn are done; dot(t+1) readers come after B1(t+1))
        if (layer == 0 && tid >= 256 && tid < 256 + 10 && t + 1 < T_STEPS) {
            ((float4*)bufn)[tid - 256] = ((const float4*)(x63 + (t + 1) * F_IN))[tid - 256];
        }

        // ---- 128-wide partial dot, 4 independent accumulator chains ----
        float a0 = 0.f, a1 = 0.f, a2 = 0.f, a3 = 0.f;
        const float* in = buf + seg * 128;
        const int rot = seg * 8;
        #pragma unroll
        for (int k4 = 0; k4 < 32; k4++) {
            int base = (k4 * 4 + rot) & 127;
            a0 += w[k4 * 4 + 0] * in[base + 0];
            a1 += w[k4 * 4 + 1] * in[base + 1];
            a2 += w[k4 * 4 + 2] * in[base + 2];
            a3 += w[k4 * 4 + 3] * in[base + 3];
        }
        float acc = (a0 + a1) + (a2 + a3) + bias;
        // sum the 4 k-segments (lanes tid^1, tid^2 within the quad)
        acc += __shfl_xor(acc, 1, 64);
        acc += __shfl_xor(acc, 2, 64);
        // gate exchange across the 4 quads of this j's 16-lane group:
        // for a lane in quad q: vf = gate(q^1), vg = gate(q^2), vo = gate(q^3)
        float vf = __shfl_xor(acc, 4, 64);
        float vg = __shfl_xor(acc, 8, 64);
        float vo = __shfl_xor(vf, 8, 64);

        if (is_upd) {   // quad 0, seg 0 -> acc=i, vf=f, vg=g, vo=o
            float si = fast_sig(acc);
            float sf = fast_sig(vf);
            float so = fast_sig(vo);
            c_state = sf * c_state + si * fast_tanh(vg);
            float hv = so * fast_tanh(c_state);
            unsigned long long word =
                ((unsigned long long)(unsigned)(t + 1) << 32) | (unsigned long long)__float_as_uint(hv);
            // publish first (siblings' critical path), then local bookkeeping
            __hip_atomic_store(h_own + (size_t)(t + 1) * HID + g * 32 + j, word,
                               __ATOMIC_RELAXED, __HIP_MEMORY_SCOPE_AGENT);
            bufn[256 + g * 32 + j] = hv;   // own h for our next step, no global round-trip
            if (layer == 2) h2f[(size_t)t * HID + g * 32 + j] = hv;
        }
        // no fence / flag needed: tag rides in the same atomic word
    }
}

// ---------------- K3: logits = h2 @ w_lin^T + b_lin (tiled fp32 GEMM) ----------------
#define BM 64
#define BN 64
#define BK 32
__global__ __launch_bounds__(256) void k3_logits(
    const float* __restrict__ A, const float* __restrict__ w_lin,
    const float* __restrict__ b_lin, float* __restrict__ out)
{
    int m0 = blockIdx.x * BM;
    int n0 = blockIdx.y * BN;
    int tid = threadIdx.x;
    __shared__ float As[BM][BK + 1];
    __shared__ float Bs[BN][BK + 1];
    float accv[4][4] = {};
    int tx = tid % 16, ty = tid / 16;

    for (int k0 = 0; k0 < HID; k0 += BK) {
        int row = tid / 4;
        int kq  = (tid % 4) * 8;
        {
            const float4* src = (const float4*)(A + (m0 + row) * HID + k0 + kq);
            float4 v0 = src[0], v1 = src[1];
            As[row][kq + 0] = v0.x; As[row][kq + 1] = v0.y; As[row][kq + 2] = v0.z; As[row][kq + 3] = v0.w;
            As[row][kq + 4] = v1.x; As[row][kq + 5] = v1.y; As[row][kq + 6] = v1.z; As[row][kq + 7] = v1.w;
        }
        {
            int n = n0 + row;
            float4 v0 = make_float4(0.f, 0.f, 0.f, 0.f), v1 = v0;
            if (n < NSPK) {
                const float4* src = (const float4*)(w_lin + n * HID + k0 + kq);
                v0 = src[0]; v1 = src[1];
            }
            Bs[row][kq + 0] = v0.x; Bs[row][kq + 1] = v0.y; Bs[row][kq + 2] = v0.z; Bs[row][kq + 3] = v0.w;
            Bs[row][kq + 4] = v1.x; Bs[row][kq + 5] = v1.y; Bs[row][kq + 6] = v1.z; Bs[row][kq + 7] = v1.w;
        }
        __syncthreads();
        #pragma unroll
        for (int kk = 0; kk < BK; kk++) {
            float a0 = As[ty * 4 + 0][kk], a1 = As[ty * 4 + 1][kk];
            float a2 = As[ty * 4 + 2][kk], a3 = As[ty * 4 + 3][kk];
            float b0 = Bs[tx * 4 + 0][kk], b1 = Bs[tx * 4 + 1][kk];
            float b2 = Bs[tx * 4 + 2][kk], b3 = Bs[tx * 4 + 3][kk];
            accv[0][0] += a0 * b0; accv[0][1] += a0 * b1; accv[0][2] += a0 * b2; accv[0][3] += a0 * b3;
            accv[1][0] += a1 * b0; accv[1][1] += a1 * b1; accv[1][2] += a1 * b2; accv[1][3] += a1 * b3;
            accv[2][0] += a2 * b0; accv[2][1] += a2 * b1; accv[2][2] += a2 * b2; accv[2][3] += a2 * b3;
            accv[3][0] += a3 * b0; accv[3][1] += a3 * b1; accv[3][2] += a3 * b2; accv[3][3] += a3 * b3;
        }
        __syncthreads();
    }
    #pragma unroll
    for (int i = 0; i < 4; i++) {
        int m = m0 + ty * 4 + i;
        #pragma unroll
        for (int j = 0; j < 4; j++) {
            int n = n0 + tx * 4 + j;
            if (n < NSPK) out[(size_t)m * NSPK + n] = accv[i][j] + b_lin[n];
        }
    }
}

// ---------------- K4: in-place row-wise log_softmax over NSPK ----------------
__global__ __launch_bounds__(256) void k4_logsoftmax(float* __restrict__ out)
{
    int t = blockIdx.x;
    float* row = out + (size_t)t * NSPK;
    int tid = threadIdx.x;
    __shared__ float red[8];
    float vals[5];
    float lmax = -1e30f;
    #pragma unroll
    for (int k = 0; k < 5; k++) {
        int n = tid + k * 256;
        vals[k] = (n < NSPK) ? row[n] : -1e30f;
        lmax = fmaxf(lmax, vals[k]);
    }
    #pragma unroll
    for (int m = 1; m < 64; m <<= 1) lmax = fmaxf(lmax, __shfl_xor(lmax, m, 64));
    int wave = tid >> 6;
    if ((tid & 63) == 0) red[wave] = lmax;
    __syncthreads();
    float gmax = fmaxf(fmaxf(red[0], red[1]), fmaxf(red[2], red[3]));
    float lsum = 0.f;
    #pragma unroll
    for (int k = 0; k < 5; k++) {
        int n = tid + k * 256;
        if (n < NSPK) lsum += __expf(vals[k] - gmax);
    }
    #pragma unroll
    for (int m = 1; m < 64; m <<= 1) lsum += __shfl_xor(lsum, m, 64);
    if ((tid & 63) == 0) red[4 + wave] = lsum;
    __syncthreads();
    float lse = logf(red[4] + red[5] + red[6] + red[7]) + gmax;
    #pragma unroll
    for (int k = 0; k < 5; k++) {
        int n = tid + k * 256;
        if (n < NSPK) row[n] = vals[k] - lse;
    }
}

extern "C" void kernel_launch(void* const* d_in, const int* in_sizes, int n_in,
                              void* d_out, int out_size, void* d_ws, size_t ws_size,
                              hipStream_t stream) {
    const float* x     = (const float*)d_in[0];
    const float* w_ih0 = (const float*)d_in[1];
    const float* w_hh0 = (const float*)d_in[2];
    const float* b_ih0 = (const float*)d_in[3];
    const float* b_hh0 = (const float*)d_in[4];
    const float* w_ih1 = (const float*)d_in[5];
    const float* w_hh1 = (const float*)d_in[6];
    const float* b_ih1 = (const float*)d_in[7];
    const float* b_hh1 = (const float*)d_in[8];
    const float* w_ih2 = (const float*)d_in[9];
    const float* w_hh2 = (const float*)d_in[10];
    const float* b_ih2 = (const float*)d_in[11];
    const float* b_hh2 = (const float*)d_in[12];
    const float* w_lin = (const float*)d_in[13];
    const float* b_lin = (const float*)d_in[14];

    unsigned long long* hbuf = (unsigned long long*)d_ws;
    float* h2f = (float*)((char*)d_ws + H2F_OFF_BYTES);
    float* out = (float*)d_out;

    k0_init<<<1, 1024, 0, stream>>>(hbuf);
    k2_lstm<<<NBLOCKS, K2_THREADS, 0, stream>>>(
        x, w_ih0, w_hh0, b_ih0, b_hh0,
        w_ih1, w_hh1, b_ih1, b_hh1,
        w_ih2, w_hh2, b_ih2, b_hh2,
        hbuf, h2f);
    k3_logits<<<dim3(16, 20), 256, 0, stream>>>(h2f, w_lin, b_lin, out);
    k4_logsoftmax<<<T_STEPS, 256, 0, stream>>>(out);
}

// Round 2
// 1972.000 us; speedup vs baseline: 1.1608x; 1.1608x over previous
//
#include <hip/hip_runtime.h>

#define HID 256
#define T_STEPS 1024
#define F_IN 40
#define NSPK 1251
#define NCHUNK 8            // workgroups per layer
#define NBLOCKS (3 * NCHUNK)
#define K2_THREADS 512

// workspace layout:
//   tagged h words: u64 hbuf[3][1025][256]   (tag = time index, low 32 = float bits)
//   plain float h2f[1024][256] for the logits GEMM
#define HBUF_WORDS (3 * 1025 * 256)
#define H2F_OFF_BYTES ((size_t)HBUF_WORDS * 8)

__device__ __forceinline__ float fast_sig(float v) {
    return __builtin_amdgcn_rcpf(1.f + __expf(-v));
}
__device__ __forceinline__ float fast_tanh(float v) {
    return 2.f * __builtin_amdgcn_rcpf(1.f + __expf(-2.f * v)) - 1.f;
}

// ---------------- K0: init h[l][0][:] = (tag 0 | 0.0f) ----------------
__global__ void k0_init(unsigned long long* __restrict__ hbuf) {
    int tid = threadIdx.x;
    if (tid < 3 * HID) {
        int l = tid / HID, k = tid % HID;
        hbuf[(size_t)(l * 1025 + 0) * HID + k] = 0ull;   // tag 0, value 0.0f
    }
}

// ---------------- K2: pipelined 3-layer LSTM, tagged-word sync ----------------
// Thread mapping (per block = one layer-chunk of 32 h-indices):
//   j   = tid >> 4   (0..31)  h-index within chunk
//   seg = tid & 15   (0..15)  32-wide k-segment of the 512-wide [input(256); own-h(256)]
// Register blocking R=4: each thread holds ALL FOUR gate rows (i,f,g,o) of its j for
// its 32-k slice -> each LDS read feeds 4 FMAs (LDS traffic 4x lower than 1-row/thread).
// LDS reads are skewed by 2*seg so the 16 distinct lane addresses hit 16 distinct banks
// (the 4 j-lanes sharing a seg broadcast -> free).
// Gate totals land lane-local after a 16-lane butterfly; update lane (seg==0) computes
// hv, drops it in LDS; after barrier2 wave-front lanes tid<32 do ONE coalesced tagged
// 32-word publish (aggregated publish: consumers detect all 32 words in one poll quantum).
__global__ __launch_bounds__(K2_THREADS) void k2_lstm(
    const float* __restrict__ x,
    const float* __restrict__ w_ih0, const float* __restrict__ w_hh0,
    const float* __restrict__ b_ih0, const float* __restrict__ b_hh0,
    const float* __restrict__ w_ih1, const float* __restrict__ w_hh1,
    const float* __restrict__ b_ih1, const float* __restrict__ b_hh1,
    const float* __restrict__ w_ih2, const float* __restrict__ w_hh2,
    const float* __restrict__ b_ih2, const float* __restrict__ b_hh2,
    unsigned long long* __restrict__ hbuf, float* __restrict__ h2f)
{
    const int bid = blockIdx.x;
    const int layer = bid / NCHUNK;      // 0..2
    const int g     = bid % NCHUNK;      // chunk of 32 h-indices
    const int tid   = threadIdx.x;
    const int seg = tid & 15;            // k-segment 0..15 (32 wide each)
    const int j   = tid >> 4;            // 0..31 local h-index
    const int jg  = g * 32 + j;          // global h-index within layer

    const float* wih = (layer == 0) ? w_ih0 : (layer == 1) ? w_ih1 : w_ih2;
    const float* whh = (layer == 0) ? w_hh0 : (layer == 1) ? w_hh1 : w_hh2;
    const float* bih = (layer == 0) ? b_ih0 : (layer == 1) ? b_ih1 : b_ih2;
    const float* bhh = (layer == 0) ? b_hh0 : (layer == 1) ? b_hh1 : b_hh2;

    __shared__ float buf[512];       // [0:256] input vec (x row / prev-layer h), [256:512] own h
    __shared__ float hv_lds[32];     // this chunk's fresh h values

    // ---- load weights: w[q][i] = W_row(q)[ k(seg,i) ], k(seg,i) = seg*32 + ((i+2*seg)&31)
    // (skewed so the LDS dot below is bank-conflict-free) ----
    float w[4][32];
    float bb[4];
    const int rot = (2 * seg) & 31;
    #pragma unroll
    for (int q = 0; q < 4; q++) {
        const int r = q * 256 + jg;
        bb[q] = bih[r] + bhh[r];
        if (layer > 0) {
            #pragma unroll
            for (int i = 0; i < 32; i++) {
                int k = seg * 32 + ((i + rot) & 31);
                w[q][i] = (k < HID) ? wih[(size_t)r * HID + k]
                                    : whh[(size_t)r * HID + (k - HID)];
            }
        } else {
            #pragma unroll
            for (int i = 0; i < 32; i++) {
                int k = seg * 32 + ((i + rot) & 31);
                w[q][i] = (k < F_IN) ? w_ih0[r * F_IN + k]
                        : (k >= HID) ? whh[(size_t)r * HID + (k - HID)]
                                     : 0.f;
            }
        }
    }

    for (int i = tid; i < 512; i += K2_THREADS) buf[i] = 0.f;
    if (tid < 32) hv_lds[tid] = 0.f;   // h(0) = 0 for the own-chunk LDS path
    __syncthreads();

    const float* x63 = x + 63 * T_STEPS * F_IN;
    const unsigned long long* h_prev_layer = hbuf + (size_t)(layer - 1) * 1025 * HID; // layer>0 only
    unsigned long long* h_own              = hbuf + (size_t)layer * 1025 * HID;

    float4 px = make_float4(0.f, 0.f, 0.f, 0.f);   // layer-0 x-row prefetch (lanes 256..265)
    if (layer == 0 && tid >= 256 && tid < 256 + 10)
        px = ((const float4*)x63)[tid - 256];

    float c_state = 0.f;               // valid on update lanes (seg==0)

    for (int t = 0; t < T_STEPS; t++) {
        // ---- gather inputs (safe: all dot(t-1) readers passed barrier2(t-1)) ----
        if (tid < 256) {
            if ((tid >> 5) == g) {
                // own chunk: h(t) is last step's hv, still in LDS — no global round-trip
                buf[256 + tid] = hv_lds[tid & 31];
            } else {
                // sibling chunks' h[t], expected tag = t
                const unsigned long long* p = h_own + (size_t)t * HID + tid;
                unsigned long long v;
                do {
                    v = __hip_atomic_load(p, __ATOMIC_RELAXED, __HIP_MEMORY_SCOPE_AGENT);
                } while ((unsigned)(v >> 32) != (unsigned)t);
                buf[256 + tid] = __uint_as_float((unsigned)v);
            }
        } else if (layer > 0) {
            // prev-layer h[t+1], expected tag = t+1
            const unsigned long long* p = h_prev_layer + (size_t)(t + 1) * HID + (tid - 256);
            unsigned long long v;
            do {
                v = __hip_atomic_load(p, __ATOMIC_RELAXED, __HIP_MEMORY_SCOPE_AGENT);
            } while ((unsigned)(v >> 32) != (unsigned)(t + 1));
            buf[tid - 256] = __uint_as_float((unsigned)v);
        } else if (tid < 256 + 10) {
            // layer 0: write prefetched x row t, then issue load of row t+1
            // (completes during the dot; written to LDS next iteration)
            ((float4*)buf)[tid - 256] = px;
            if (t + 1 < T_STEPS)
                px = ((const float4*)(x63 + (t + 1) * F_IN))[tid - 256];
        }
        __syncthreads();   // barrier 1

        // ---- 32-wide skewed LDS dot, 4 gate rows per thread (R=4 blocking) ----
        float a0 = 0.f, a1 = 0.f, a2 = 0.f, a3 = 0.f;
        const float* bufs = buf + seg * 32;
        #pragma unroll
        for (int i = 0; i < 32; i++) {
            float f = bufs[(i + rot) & 31];
            a0 += w[0][i] * f;
            a1 += w[1][i] * f;
            a2 += w[2][i] * f;
            a3 += w[3][i] * f;
        }
        // reduce each gate over the 16 seg-lanes (butterfly; j-group preserved, masks<16)
        #pragma unroll
        for (int m = 1; m < 16; m <<= 1) {
            a0 += __shfl_xor(a0, m, 64);
            a1 += __shfl_xor(a1, m, 64);
            a2 += __shfl_xor(a2, m, 64);
            a3 += __shfl_xor(a3, m, 64);
        }

        if (seg == 0) {   // update lane for h-index j
            float si = fast_sig(a0 + bb[0]);
            float sf = fast_sig(a1 + bb[1]);
            float gg = fast_tanh(a2 + bb[2]);
            float so = fast_sig(a3 + bb[3]);
            c_state = sf * c_state + si * gg;
            float hv = so * fast_tanh(c_state);
            hv_lds[j] = hv;
        }
        __syncthreads();   // barrier 2

        // ---- aggregated coalesced publish: ONE 32-lane tagged store ----
        if (tid < 32) {
            float hv = hv_lds[tid];
            unsigned long long word =
                ((unsigned long long)(unsigned)(t + 1) << 32) | (unsigned long long)__float_as_uint(hv);
            __hip_atomic_store(h_own + (size_t)(t + 1) * HID + g * 32 + tid, word,
                               __ATOMIC_RELAXED, __HIP_MEMORY_SCOPE_AGENT);
            if (layer == 2) h2f[(size_t)t * HID + g * 32 + tid] = hv;
        }
        // no fence / flag needed: tag rides in the same atomic word
    }
}

// ---------------- K3: logits = h2 @ w_lin^T + b_lin (tiled fp32 GEMM) ----------------
#define BM 64
#define BN 64
#define BK 32
__global__ __launch_bounds__(256) void k3_logits(
    const float* __restrict__ A, const float* __restrict__ w_lin,
    const float* __restrict__ b_lin, float* __restrict__ out)
{
    int m0 = blockIdx.x * BM;
    int n0 = blockIdx.y * BN;
    int tid = threadIdx.x;
    __shared__ float As[BM][BK + 1];
    __shared__ float Bs[BN][BK + 1];
    float accv[4][4] = {};
    int tx = tid % 16, ty = tid / 16;

    for (int k0 = 0; k0 < HID; k0 += BK) {
        int row = tid / 4;
        int kq  = (tid % 4) * 8;
        {
            const float4* src = (const float4*)(A + (m0 + row) * HID + k0 + kq);
            float4 v0 = src[0], v1 = src[1];
            As[row][kq + 0] = v0.x; As[row][kq + 1] = v0.y; As[row][kq + 2] = v0.z; As[row][kq + 3] = v0.w;
            As[row][kq + 4] = v1.x; As[row][kq + 5] = v1.y; As[row][kq + 6] = v1.z; As[row][kq + 7] = v1.w;
        }
        {
            int n = n0 + row;
            float4 v0 = make_float4(0.f, 0.f, 0.f, 0.f), v1 = v0;
            if (n < NSPK) {
                const float4* src = (const float4*)(w_lin + n * HID + k0 + kq);
                v0 = src[0]; v1 = src[1];
            }
            Bs[row][kq + 0] = v0.x; Bs[row][kq + 1] = v0.y; Bs[row][kq + 2] = v0.z; Bs[row][kq + 3] = v0.w;
            Bs[row][kq + 4] = v1.x; Bs[row][kq + 5] = v1.y; Bs[row][kq + 6] = v1.z; Bs[row][kq + 7] = v1.w;
        }
        __syncthreads();
        #pragma unroll
        for (int kk = 0; kk < BK; kk++) {
            float a0 = As[ty * 4 + 0][kk], a1 = As[ty * 4 + 1][kk];
            float a2 = As[ty * 4 + 2][kk], a3 = As[ty * 4 + 3][kk];
            float b0 = Bs[tx * 4 + 0][kk], b1 = Bs[tx * 4 + 1][kk];
            float b2 = Bs[tx * 4 + 2][kk], b3 = Bs[tx * 4 + 3][kk];
            accv[0][0] += a0 * b0; accv[0][1] += a0 * b1; accv[0][2] += a0 * b2; accv[0][3] += a0 * b3;
            accv[1][0] += a1 * b0; accv[1][1] += a1 * b1; accv[1][2] += a1 * b2; accv[1][3] += a1 * b3;
            accv[2][0] += a2 * b0; accv[2][1] += a2 * b1; accv[2][2] += a2 * b2; accv[2][3] += a2 * b3;
            accv[3][0] += a3 * b0; accv[3][1] += a3 * b1; accv[3][2] += a3 * b2; accv[3][3] += a3 * b3;
        }
        __syncthreads();
    }
    #pragma unroll
    for (int i = 0; i < 4; i++) {
        int m = m0 + ty * 4 + i;
        #pragma unroll
        for (int j = 0; j < 4; j++) {
            int n = n0 + tx * 4 + j;
            if (n < NSPK) out[(size_t)m * NSPK + n] = accv[i][j] + b_lin[n];
        }
    }
}

// ---------------- K4: in-place row-wise log_softmax over NSPK ----------------
__global__ __launch_bounds__(256) void k4_logsoftmax(float* __restrict__ out)
{
    int t = blockIdx.x;
    float* row = out + (size_t)t * NSPK;
    int tid = threadIdx.x;
    __shared__ float red[8];
    float vals[5];
    float lmax = -1e30f;
    #pragma unroll
    for (int k = 0; k < 5; k++) {
        int n = tid + k * 256;
        vals[k] = (n < NSPK) ? row[n] : -1e30f;
        lmax = fmaxf(lmax, vals[k]);
    }
    #pragma unroll
    for (int m = 1; m < 64; m <<= 1) lmax = fmaxf(lmax, __shfl_xor(lmax, m, 64));
    int wave = tid >> 6;
    if ((tid & 63) == 0) red[wave] = lmax;
    __syncthreads();
    float gmax = fmaxf(fmaxf(red[0], red[1]), fmaxf(red[2], red[3]));
    float lsum = 0.f;
    #pragma unroll
    for (int k = 0; k < 5; k++) {
        int n = tid + k * 256;
        if (n < NSPK) lsum += __expf(vals[k] - gmax);
    }
    #pragma unroll
    for (int m = 1; m < 64; m <<= 1) lsum += __shfl_xor(lsum, m, 64);
    if ((tid & 63) == 0) red[4 + wave] = lsum;
    __syncthreads();
    float lse = logf(red[4] + red[5] + red[6] + red[7]) + gmax;
    #pragma unroll
    for (int k = 0; k < 5; k++) {
        int n = tid + k * 256;
        if (n < NSPK) row[n] = vals[k] - lse;
    }
}

extern "C" void kernel_launch(void* const* d_in, const int* in_sizes, int n_in,
                              void* d_out, int out_size, void* d_ws, size_t ws_size,
                              hipStream_t stream) {
    const float* x     = (const float*)d_in[0];
    const float* w_ih0 = (const float*)d_in[1];
    const float* w_hh0 = (const float*)d_in[2];
    const float* b_ih0 = (const float*)d_in[3];
    const float* b_hh0 = (const float*)d_in[4];
    const float* w_ih1 = (const float*)d_in[5];
    const float* w_hh1 = (const float*)d_in[6];
    const float* b_ih1 = (const float*)d_in[7];
    const float* b_hh1 = (const float*)d_in[8];
    const float* w_ih2 = (const float*)d_in[9];
    const float* w_hh2 = (const float*)d_in[10];
    const float* b_ih2 = (const float*)d_in[11];
    const float* b_hh2 = (const float*)d_in[12];
    const float* w_lin = (const float*)d_in[13];
    const float* b_lin = (const float*)d_in[14];

    unsigned long long* hbuf = (unsigned long long*)d_ws;
    float* h2f = (float*)((char*)d_ws + H2F_OFF_BYTES);
    float* out = (float*)d_out;

    k0_init<<<1, 1024, 0, stream>>>(hbuf);
    k2_lstm<<<NBLOCKS, K2_THREADS, 0, stream>>>(
        x, w_ih0, w_hh0, b_ih0, b_hh0,
        w_ih1, w_hh1, b_ih1, b_hh1,
        w_ih2, w_hh2, b_ih2, b_hh2,
        hbuf, h2f);
    k3_logits<<<dim3(16, 20), 256, 0, stream>>>(h2f, w_lin, b_lin, out);
    k4_logsoftmax<<<T_STEPS, 256, 0, stream>>>(out);
}

// Round 3
// 1864.071 us; speedup vs baseline: 1.2280x; 1.0579x over previous
//
#include <hip/hip_runtime.h>

#define HID 256
#define T_STEPS 1024
#define F_IN 40
#define NSPK 1251
#define NCHUNK 8            // workgroups per layer
#define NBLOCKS 64          // 8 XCD slots x 8 chunks; blocks with (bid&7)>=3 exit
#define K2_THREADS 512

// workspace layout:
//   tagged h words: u64 hbuf[3][1025][256]   (tag = time index, low 32 = float bits)
//   plain float h2f[1024][256] for the logits GEMM
#define HBUF_WORDS (3 * 1025 * 256)
#define H2F_OFF_BYTES ((size_t)HBUF_WORDS * 8)

__device__ __forceinline__ float fast_sig(float v) {
    return __builtin_amdgcn_rcpf(1.f + __expf(-v));
}
__device__ __forceinline__ float fast_tanh(float v) {
    return 2.f * __builtin_amdgcn_rcpf(1.f + __expf(-2.f * v)) - 1.f;
}

// Pipelined tagged-word poll: keep 4 independent same-address loads in flight so the
// sampling period is ~RTT/4 instead of a full dependent-load RTT per sample.
// Accepting any sample whose tag matches is order-safe (producer writes the word once).
__device__ __forceinline__ float poll_word(const unsigned long long* p, unsigned want) {
    unsigned long long v0 = __hip_atomic_load(p, __ATOMIC_RELAXED, __HIP_MEMORY_SCOPE_AGENT);
    if ((unsigned)(v0 >> 32) == want) return __uint_as_float((unsigned)v0);  // steady-state hit
    unsigned long long v1 = __hip_atomic_load(p, __ATOMIC_RELAXED, __HIP_MEMORY_SCOPE_AGENT);
    unsigned long long v2 = __hip_atomic_load(p, __ATOMIC_RELAXED, __HIP_MEMORY_SCOPE_AGENT);
    unsigned long long v3 = __hip_atomic_load(p, __ATOMIC_RELAXED, __HIP_MEMORY_SCOPE_AGENT);
    for (;;) {
        if ((unsigned)(v0 >> 32) == want) return __uint_as_float((unsigned)v0);
        v0 = v1; v1 = v2; v2 = v3;
        v3 = __hip_atomic_load(p, __ATOMIC_RELAXED, __HIP_MEMORY_SCOPE_AGENT);
    }
}

// ---------------- K0: init h[l][0][:] = (tag 0 | 0.0f) ----------------
__global__ void k0_init(unsigned long long* __restrict__ hbuf) {
    int tid = threadIdx.x;
    if (tid < 3 * HID) {
        int l = tid / HID, k = tid % HID;
        hbuf[(size_t)(l * 1025 + 0) * HID + k] = 0ull;   // tag 0, value 0.0f
    }
}

// ---------------- K2: pipelined 3-layer LSTM, tagged-word sync ----------------
// Block mapping: assuming round-robin blockIdx%8 -> XCD, blocks are laid out as
// bid = g*8 + layer so ALL 8 chunks of a layer share one XCD's L2 (shortest
// publish->detect path if agent atomics coherence-point intra-XCD; neutral if not).
// Thread mapping (per block = one layer-chunk of 32 h-indices):
//   j   = tid >> 4   (0..31)  h-index within chunk
//   seg = tid & 15   (0..15)  32-wide k-segment of the 512-wide [input(256); own-h(256)]
// Register blocking R=4: each thread holds ALL FOUR gate rows (i,f,g,o) of its j for
// its 32-k slice -> each LDS read feeds 4 FMAs. Reads skewed by 2*seg: conflict-free.
// Gate totals land lane-local after a 16-lane butterfly; update lane (seg==0) computes
// hv, drops it in LDS; after barrier2 lanes tid<32 do ONE coalesced tagged 32-word
// publish (aggregated publish: consumers detect all 32 words in one poll quantum).
__global__ __launch_bounds__(K2_THREADS) void k2_lstm(
    const float* __restrict__ x,
    const float* __restrict__ w_ih0, const float* __restrict__ w_hh0,
    const float* __restrict__ b_ih0, const float* __restrict__ b_hh0,
    const float* __restrict__ w_ih1, const float* __restrict__ w_hh1,
    const float* __restrict__ b_ih1, const float* __restrict__ b_hh1,
    const float* __restrict__ w_ih2, const float* __restrict__ w_hh2,
    const float* __restrict__ b_ih2, const float* __restrict__ b_hh2,
    unsigned long long* __restrict__ hbuf, float* __restrict__ h2f)
{
    const int bid = blockIdx.x;
    const int xslot = bid & 7;           // XCD slot under round-robin dispatch
    if (xslot >= 3) return;              // only 3 layers; 40 of 64 blocks idle-exit
    const int layer = xslot;             // all 8 chunks of a layer share an XCD
    const int g     = bid >> 3;          // chunk of 32 h-indices
    const int tid   = threadIdx.x;
    const int seg = tid & 15;            // k-segment 0..15 (32 wide each)
    const int j   = tid >> 4;            // 0..31 local h-index
    const int jg  = g * 32 + j;          // global h-index within layer

    const float* wih = (layer == 0) ? w_ih0 : (layer == 1) ? w_ih1 : w_ih2;
    const float* whh = (layer == 0) ? w_hh0 : (layer == 1) ? w_hh1 : w_hh2;
    const float* bih = (layer == 0) ? b_ih0 : (layer == 1) ? b_ih1 : b_ih2;
    const float* bhh = (layer == 0) ? b_hh0 : (layer == 1) ? b_hh1 : b_hh2;

    __shared__ float buf[512];       // [0:256] input vec (x row / prev-layer h), [256:512] own h
    __shared__ float hv_lds[32];     // this chunk's fresh h values

    // ---- load weights: w[q][i] = W_row(q)[ k(seg,i) ], k(seg,i) = seg*32 + ((i+2*seg)&31)
    // (skewed so the LDS dot below is bank-conflict-free) ----
    float w[4][32];
    float bb[4];
    const int rot = (2 * seg) & 31;
    #pragma unroll
    for (int q = 0; q < 4; q++) {
        const int r = q * 256 + jg;
        bb[q] = bih[r] + bhh[r];
        if (layer > 0) {
            #pragma unroll
            for (int i = 0; i < 32; i++) {
                int k = seg * 32 + ((i + rot) & 31);
                w[q][i] = (k < HID) ? wih[(size_t)r * HID + k]
                                    : whh[(size_t)r * HID + (k - HID)];
            }
        } else {
            #pragma unroll
            for (int i = 0; i < 32; i++) {
                int k = seg * 32 + ((i + rot) & 31);
                w[q][i] = (k < F_IN) ? w_ih0[r * F_IN + k]
                        : (k >= HID) ? whh[(size_t)r * HID + (k - HID)]
                                     : 0.f;
            }
        }
    }

    for (int i = tid; i < 512; i += K2_THREADS) buf[i] = 0.f;
    if (tid < 32) hv_lds[tid] = 0.f;   // h(0) = 0 for the own-chunk LDS path
    __syncthreads();

    const float* x63 = x + 63 * T_STEPS * F_IN;
    const unsigned long long* h_prev_layer = hbuf + (size_t)(layer - 1) * 1025 * HID; // layer>0 only
    unsigned long long* h_own              = hbuf + (size_t)layer * 1025 * HID;

    float4 px = make_float4(0.f, 0.f, 0.f, 0.f);   // layer-0 x-row prefetch (lanes 256..265)
    if (layer == 0 && tid >= 256 && tid < 256 + 10)
        px = ((const float4*)x63)[tid - 256];

    float c_state = 0.f;               // valid on update lanes (seg==0)

    for (int t = 0; t < T_STEPS; t++) {
        // ---- gather inputs (safe: all dot(t-1) readers passed barrier2(t-1)) ----
        if (tid < 256) {
            if ((tid >> 5) == g) {
                // own chunk: h(t) is last step's hv, still in LDS — no global round-trip
                buf[256 + tid] = hv_lds[tid & 31];
            } else {
                // sibling chunks' h[t], expected tag = t (pipelined poll)
                buf[256 + tid] = poll_word(h_own + (size_t)t * HID + tid, (unsigned)t);
            }
        } else if (layer > 0) {
            // prev-layer h[t+1], expected tag = t+1 (pipelined poll)
            buf[tid - 256] = poll_word(h_prev_layer + (size_t)(t + 1) * HID + (tid - 256),
                                       (unsigned)(t + 1));
        } else if (tid < 256 + 10) {
            // layer 0: write prefetched x row t, then issue load of row t+1
            // (completes during the dot; written to LDS next iteration)
            ((float4*)buf)[tid - 256] = px;
            if (t + 1 < T_STEPS)
                px = ((const float4*)(x63 + (t + 1) * F_IN))[tid - 256];
        }
        __syncthreads();   // barrier 1

        // ---- 32-wide skewed LDS dot, 4 gate rows per thread (R=4 blocking) ----
        float a0 = 0.f, a1 = 0.f, a2 = 0.f, a3 = 0.f;
        const float* bufs = buf + seg * 32;
        #pragma unroll
        for (int i = 0; i < 32; i++) {
            float f = bufs[(i + rot) & 31];
            a0 += w[0][i] * f;
            a1 += w[1][i] * f;
            a2 += w[2][i] * f;
            a3 += w[3][i] * f;
        }
        // reduce each gate over the 16 seg-lanes (butterfly; j-group preserved, masks<16)
        #pragma unroll
        for (int m = 1; m < 16; m <<= 1) {
            a0 += __shfl_xor(a0, m, 64);
            a1 += __shfl_xor(a1, m, 64);
            a2 += __shfl_xor(a2, m, 64);
            a3 += __shfl_xor(a3, m, 64);
        }

        if (seg == 0) {   // update lane for h-index j
            float si = fast_sig(a0 + bb[0]);
            float sf = fast_sig(a1 + bb[1]);
            float gg = fast_tanh(a2 + bb[2]);
            float so = fast_sig(a3 + bb[3]);
            c_state = sf * c_state + si * gg;
            float hv = so * fast_tanh(c_state);
            hv_lds[j] = hv;
        }
        __syncthreads();   // barrier 2

        // ---- aggregated coalesced publish: ONE 32-lane tagged store ----
        if (tid < 32) {
            float hv = hv_lds[tid];
            unsigned long long word =
                ((unsigned long long)(unsigned)(t + 1) << 32) | (unsigned long long)__float_as_uint(hv);
            __hip_atomic_store(h_own + (size_t)(t + 1) * HID + g * 32 + tid, word,
                               __ATOMIC_RELAXED, __HIP_MEMORY_SCOPE_AGENT);
            if (layer == 2) h2f[(size_t)t * HID + g * 32 + tid] = hv;
        }
        // no fence / flag needed: tag rides in the same atomic word
    }
}

// ---------------- K3: logits = h2 @ w_lin^T + b_lin (tiled fp32 GEMM) ----------------
#define BM 64
#define BN 64
#define BK 32
__global__ __launch_bounds__(256) void k3_logits(
    const float* __restrict__ A, const float* __restrict__ w_lin,
    const float* __restrict__ b_lin, float* __restrict__ out)
{
    int m0 = blockIdx.x * BM;
    int n0 = blockIdx.y * BN;
    int tid = threadIdx.x;
    __shared__ float As[BM][BK + 1];
    __shared__ float Bs[BN][BK + 1];
    float accv[4][4] = {};
    int tx = tid % 16, ty = tid / 16;

    for (int k0 = 0; k0 < HID; k0 += BK) {
        int row = tid / 4;
        int kq  = (tid % 4) * 8;
        {
            const float4* src = (const float4*)(A + (m0 + row) * HID + k0 + kq);
            float4 v0 = src[0], v1 = src[1];
            As[row][kq + 0] = v0.x; As[row][kq + 1] = v0.y; As[row][kq + 2] = v0.z; As[row][kq + 3] = v0.w;
            As[row][kq + 4] = v1.x; As[row][kq + 5] = v1.y; As[row][kq + 6] = v1.z; As[row][kq + 7] = v1.w;
        }
        {
            int n = n0 + row;
            float4 v0 = make_float4(0.f, 0.f, 0.f, 0.f), v1 = v0;
            if (n < NSPK) {
                const float4* src = (const float4*)(w_lin + n * HID + k0 + kq);
                v0 = src[0]; v1 = src[1];
            }
            Bs[row][kq + 0] = v0.x; Bs[row][kq + 1] = v0.y; Bs[row][kq + 2] = v0.z; Bs[row][kq + 3] = v0.w;
            Bs[row][kq + 4] = v1.x; Bs[row][kq + 5] = v1.y; Bs[row][kq + 6] = v1.z; Bs[row][kq + 7] = v1.w;
        }
        __syncthreads();
        #pragma unroll
        for (int kk = 0; kk < BK; kk++) {
            float a0 = As[ty * 4 + 0][kk], a1 = As[ty * 4 + 1][kk];
            float a2 = As[ty * 4 + 2][kk], a3 = As[ty * 4 + 3][kk];
            float b0 = Bs[tx * 4 + 0][kk], b1 = Bs[tx * 4 + 1][kk];
            float b2 = Bs[tx * 4 + 2][kk], b3 = Bs[tx * 4 + 3][kk];
            accv[0][0] += a0 * b0; accv[0][1] += a0 * b1; accv[0][2] += a0 * b2; accv[0][3] += a0 * b3;
            accv[1][0] += a1 * b0; accv[1][1] += a1 * b1; accv[1][2] += a1 * b2; accv[1][3] += a1 * b3;
            accv[2][0] += a2 * b0; accv[2][1] += a2 * b1; accv[2][2] += a2 * b2; accv[2][3] += a2 * b3;
            accv[3][0] += a3 * b0; accv[3][1] += a3 * b1; accv[3][2] += a3 * b2; accv[3][3] += a3 * b3;
        }
        __syncthreads();
    }
    #pragma unroll
    for (int i = 0; i < 4; i++) {
        int m = m0 + ty * 4 + i;
        #pragma unroll
        for (int j = 0; j < 4; j++) {
            int n = n0 + tx * 4 + j;
            if (n < NSPK) out[(size_t)m * NSPK + n] = accv[i][j] + b_lin[n];
        }
    }
}

// ---------------- K4: in-place row-wise log_softmax over NSPK ----------------
__global__ __launch_bounds__(256) void k4_logsoftmax(float* __restrict__ out)
{
    int t = blockIdx.x;
    float* row = out + (size_t)t * NSPK;
    int tid = threadIdx.x;
    __shared__ float red[8];
    float vals[5];
    float lmax = -1e30f;
    #pragma unroll
    for (int k = 0; k < 5; k++) {
        int n = tid + k * 256;
        vals[k] = (n < NSPK) ? row[n] : -1e30f;
        lmax = fmaxf(lmax, vals[k]);
    }
    #pragma unroll
    for (int m = 1; m < 64; m <<= 1) lmax = fmaxf(lmax, __shfl_xor(lmax, m, 64));
    int wave = tid >> 6;
    if ((tid & 63) == 0) red[wave] = lmax;
    __syncthreads();
    float gmax = fmaxf(fmaxf(red[0], red[1]), fmaxf(red[2], red[3]));
    float lsum = 0.f;
    #pragma unroll
    for (int k = 0; k < 5; k++) {
        int n = tid + k * 256;
        if (n < NSPK) lsum += __expf(vals[k] - gmax);
    }
    #pragma unroll
    for (int m = 1; m < 64; m <<= 1) lsum += __shfl_xor(lsum, m, 64);
    if ((tid & 63) == 0) red[4 + wave] = lsum;
    __syncthreads();
    float lse = logf(red[4] + red[5] + red[6] + red[7]) + gmax;
    #pragma unroll
    for (int k = 0; k < 5; k++) {
        int n = tid + k * 256;
        if (n < NSPK) row[n] = vals[k] - lse;
    }
}

extern "C" void kernel_launch(void* const* d_in, const int* in_sizes, int n_in,
                              void* d_out, int out_size, void* d_ws, size_t ws_size,
                              hipStream_t stream) {
    const float* x     = (const float*)d_in[0];
    const float* w_ih0 = (const float*)d_in[1];
    const float* w_hh0 = (const float*)d_in[2];
    const float* b_ih0 = (const float*)d_in[3];
    const float* b_hh0 = (const float*)d_in[4];
    const float* w_ih1 = (const float*)d_in[5];
    const float* w_hh1 = (const float*)d_in[6];
    const float* b_ih1 = (const float*)d_in[7];
    const float* b_hh1 = (const float*)d_in[8];
    const float* w_ih2 = (const float*)d_in[9];
    const float* w_hh2 = (const float*)d_in[10];
    const float* b_ih2 = (const float*)d_in[11];
    const float* b_hh2 = (const float*)d_in[12];
    const float* w_lin = (const float*)d_in[13];
    const float* b_lin = (const float*)d_in[14];

    unsigned long long* hbuf = (unsigned long long*)d_ws;
    float* h2f = (float*)((char*)d_ws + H2F_OFF_BYTES);
    float* out = (float*)d_out;

    k0_init<<<1, 1024, 0, stream>>>(hbuf);
    k2_lstm<<<NBLOCKS, K2_THREADS, 0, stream>>>(
        x, w_ih0, w_hh0, b_ih0, b_hh0,
        w_ih1, w_hh1, b_ih1, b_hh1,
        w_ih2, w_hh2, b_ih2, b_hh2,
        hbuf, h2f);
    k3_logits<<<dim3(16, 20), 256, 0, stream>>>(h2f, w_lin, b_lin, out);
    k4_logsoftmax<<<T_STEPS, 256, 0, stream>>>(out);
}

// Round 4
// 1631.430 us; speedup vs baseline: 1.4031x; 1.1426x over previous
//
#include <hip/hip_runtime.h>

#define HID 256
#define T_STEPS 1024
#define F_IN 40
#define NSPK 1251
#define NCHUNK 8            // workgroups per layer
#define NBLOCKS 64          // 8 XCD slots x 8 chunks; blocks with (bid&7)>=3 exit
#define K2_THREADS 512

// workspace layout:
//   tagged h words: u64 hbuf[3][1025][256]   (tag = time index, low 32 = float bits)
//   plain float h2f[1024][256] for the logits GEMM
#define HBUF_WORDS (3 * 1025 * 256)
#define H2F_OFF_BYTES ((size_t)HBUF_WORDS * 8)

__device__ __forceinline__ float fast_sig(float v) {
    return __builtin_amdgcn_rcpf(1.f + __expf(-v));
}
__device__ __forceinline__ float fast_tanh(float v) {
    return 2.f * __builtin_amdgcn_rcpf(1.f + __expf(-2.f * v)) - 1.f;
}

// Pipelined tagged-word poll: keep 4 independent same-address loads in flight so the
// sampling period is ~RTT/4 instead of a full dependent-load RTT per sample.
__device__ __forceinline__ float poll_word(const unsigned long long* p, unsigned want) {
    unsigned long long v0 = __hip_atomic_load(p, __ATOMIC_RELAXED, __HIP_MEMORY_SCOPE_AGENT);
    if ((unsigned)(v0 >> 32) == want) return __uint_as_float((unsigned)v0);  // steady-state hit
    unsigned long long v1 = __hip_atomic_load(p, __ATOMIC_RELAXED, __HIP_MEMORY_SCOPE_AGENT);
    unsigned long long v2 = __hip_atomic_load(p, __ATOMIC_RELAXED, __HIP_MEMORY_SCOPE_AGENT);
    unsigned long long v3 = __hip_atomic_load(p, __ATOMIC_RELAXED, __HIP_MEMORY_SCOPE_AGENT);
    for (;;) {
        if ((unsigned)(v0 >> 32) == want) return __uint_as_float((unsigned)v0);
        v0 = v1; v1 = v2; v2 = v3;
        v3 = __hip_atomic_load(p, __ATOMIC_RELAXED, __HIP_MEMORY_SCOPE_AGENT);
    }
}

// ---------------- K0: init h[l][0][:] = (tag 0 | 0.0f) ----------------
__global__ void k0_init(unsigned long long* __restrict__ hbuf) {
    int tid = threadIdx.x;
    if (tid < 3 * HID) {
        int l = tid / HID, k = tid % HID;
        hbuf[(size_t)(l * 1025 + 0) * HID + k] = 0ull;   // tag 0, value 0.0f
    }
}

// ---------------- K2: pipelined 3-layer LSTM, tagged-word sync ----------------
// DS-pipe-minimized structure. Thread mapping (block = one layer-chunk of 32 h):
//   seg = tid >> 5  (0..15)  32-wide k-segment of the 512-wide [input(256); own-h(256)]
//   j   = tid & 31           h-index within chunk (every seg covers all 32 j)
//   wave w owns segs {2w, 2w+1} = k-range [64w, 64w+64) -- gather/bounce/dot are
//   wave-PRIVATE (no cross-wave buf sharing -> no barrier needed around the bounce).
// Per step per wave: poll 1 word/lane (coalesced 64 words) -> ds_write_b32 -> 8x
// broadcast ds_read_b128 + 128 FMA (R=4: 4 gate rows per thread) -> 4x shfl_xor(32)
// seg-fold -> ONE packed ds_write_b128 of the 4 gate partials into parity-double-
// buffered gatebuf -> ONE s_barrier -> wave 0 lanes 0..31 sum 8 wave-partials,
// nonlinearity, and publish immediately (single-wave coalesced 2-line tagged store).
// DS-pipe instrs/step: ~8 w + 64 r128 + 32 shfl + 8 w128 + 8 r128 (~half of R3).
__global__ __launch_bounds__(K2_THREADS) void k2_lstm(
    const float* __restrict__ x,
    const float* __restrict__ w_ih0, const float* __restrict__ w_hh0,
    const float* __restrict__ b_ih0, const float* __restrict__ b_hh0,
    const float* __restrict__ w_ih1, const float* __restrict__ w_hh1,
    const float* __restrict__ b_ih1, const float* __restrict__ b_hh1,
    const float* __restrict__ w_ih2, const float* __restrict__ w_hh2,
    const float* __restrict__ b_ih2, const float* __restrict__ b_hh2,
    unsigned long long* __restrict__ hbuf, float* __restrict__ h2f)
{
    const int bid = blockIdx.x;
    const int xslot = bid & 7;           // XCD slot under round-robin dispatch
    if (xslot >= 3) return;              // only 3 layers; 40 of 64 blocks idle-exit
    const int layer = xslot;             // all 8 chunks of a layer share an XCD
    const int g     = bid >> 3;          // chunk of 32 h-indices
    const int tid   = threadIdx.x;
    const int seg = tid >> 5;            // k-segment 0..15 (32 wide each)
    const int j   = tid & 31;            // local h-index
    const int wv  = tid >> 6;            // wave 0..7
    const int jg  = g * 32 + j;          // global h-index within layer

    const float* wih = (layer == 0) ? w_ih0 : (layer == 1) ? w_ih1 : w_ih2;
    const float* whh = (layer == 0) ? w_hh0 : (layer == 1) ? w_hh1 : w_hh2;
    const float* bih = (layer == 0) ? b_ih0 : (layer == 1) ? b_ih1 : b_ih2;
    const float* bhh = (layer == 0) ? b_hh0 : (layer == 1) ? b_hh1 : b_hh2;

    // layer 0: k in [64,256) is all-zero input -> waves 1..3 have nothing to do
    const bool dead = (layer == 0) && (seg >= 2) && (seg < 8);

    __shared__ float  buf[512];          // bounce buffer; wave-private 64-word regions
    __shared__ float4 gatebuf[2][8][32]; // [t-parity][wave][j] = 4 gate partials

    // ---- weights: w[q][i] = W_row(q*256+jg)[ seg*32 + i ]  (contiguous, no skew) ----
    float w[4][32];
    float bb[4];
    if (!dead) {
        #pragma unroll
        for (int q = 0; q < 4; q++) {
            const int r = q * 256 + jg;
            bb[q] = bih[r] + bhh[r];
            const int k0 = seg * 32;
            if (k0 >= 256) {
                const float4* src = (const float4*)(whh + (size_t)r * HID + (k0 - 256));
                #pragma unroll
                for (int i4 = 0; i4 < 8; i4++) {
                    float4 v = src[i4];
                    w[q][i4*4+0] = v.x; w[q][i4*4+1] = v.y;
                    w[q][i4*4+2] = v.z; w[q][i4*4+3] = v.w;
                }
            } else if (layer > 0) {
                const float4* src = (const float4*)(wih + (size_t)r * HID + k0);
                #pragma unroll
                for (int i4 = 0; i4 < 8; i4++) {
                    float4 v = src[i4];
                    w[q][i4*4+0] = v.x; w[q][i4*4+1] = v.y;
                    w[q][i4*4+2] = v.z; w[q][i4*4+3] = v.w;
                }
            } else {
                // layer 0, seg 0/1: 40-wide x projection, zero-padded
                #pragma unroll
                for (int i = 0; i < 32; i++) {
                    int k = k0 + i;
                    w[q][i] = (k < F_IN) ? w_ih0[r * F_IN + k] : 0.f;
                }
            }
        }
    } else {
        #pragma unroll
        for (int q = 0; q < 4; q++) {
            bb[q] = 0.f;
            #pragma unroll
            for (int i = 0; i < 32; i++) w[q][i] = 0.f;
        }
    }

    for (int i = tid; i < 512; i += K2_THREADS) buf[i] = 0.f;
    __syncthreads();

    const float* x63 = x + 63 * T_STEPS * F_IN;
    const unsigned long long* h_prev = hbuf + (size_t)(layer - 1) * 1025 * HID; // layer>0 only
    unsigned long long* h_own        = hbuf + (size_t)layer * 1025 * HID;

    float px = 0.f;                      // layer-0 x prefetch (lanes tid<40)
    if (layer == 0 && tid < F_IN) px = x63[tid];

    float c_state = 0.f;                 // valid on tid<32 (update lanes, wave 0)

    for (int t = 0; t < T_STEPS; t++) {
        // ---- gather: each lane polls/loads word tid of the 512-wide input vec ----
        if (!dead) {
            if (tid < 256) {
                if (layer > 0) {
                    // prev-layer h[t+1] (pre-available in steady state -> 1st-try hit)
                    buf[tid] = poll_word(h_prev + (size_t)(t + 1) * HID + tid,
                                         (unsigned)(t + 1));
                } else if (tid < F_IN) {
                    buf[tid] = px;       // prefetched x[t]; issue load of x[t+1]
                    if (t + 1 < T_STEPS) px = x63[(t + 1) * F_IN + tid];
                }
                // layer 0, 40 <= tid < 256: stays 0 (weights there are 0 too)
            } else {
                // own-layer h[t] incl. own chunk (own publish -> same-XCD L2, cheap)
                buf[tid] = poll_word(h_own + (size_t)t * HID + (tid - 256),
                                     (unsigned)t);
            }
        }

        // ---- wave-private bounce: ds_write above, broadcast ds_read_b128 below.
        // Same wave, in-order DS; explicit waitcnt guards compiler scheduling. ----
        float4 part = make_float4(0.f, 0.f, 0.f, 0.f);
        if (!dead) {
            __asm__ volatile("s_waitcnt lgkmcnt(0)" ::: "memory");
            const float4* b4 = (const float4*)buf + seg * 8;
            float a0 = 0.f, a1 = 0.f, a2 = 0.f, a3 = 0.f;
            #pragma unroll
            for (int i4 = 0; i4 < 8; i4++) {
                float4 f = b4[i4];
                a0 += w[0][i4*4+0]*f.x + w[0][i4*4+1]*f.y + w[0][i4*4+2]*f.z + w[0][i4*4+3]*f.w;
                a1 += w[1][i4*4+0]*f.x + w[1][i4*4+1]*f.y + w[1][i4*4+2]*f.z + w[1][i4*4+3]*f.w;
                a2 += w[2][i4*4+0]*f.x + w[2][i4*4+1]*f.y + w[2][i4*4+2]*f.z + w[2][i4*4+3]*f.w;
                a3 += w[3][i4*4+0]*f.x + w[3][i4*4+1]*f.y + w[3][i4*4+2]*f.z + w[3][i4*4+3]*f.w;
            }
            // fold the wave's two segs (lanes L and L^32 share j)
            a0 += __shfl_xor(a0, 32, 64);
            a1 += __shfl_xor(a1, 32, 64);
            a2 += __shfl_xor(a2, 32, 64);
            a3 += __shfl_xor(a3, 32, 64);
            part = make_float4(a0, a1, a2, a3);
        }
        // one packed b128 write per wave (lanes 0..31): full-rate, conflict-free
        if ((tid & 32) == 0) gatebuf[t & 1][wv][j] = part;
        __syncthreads();                 // the ONLY barrier per step

        // ---- update + immediate aggregated publish (wave 0, lanes 0..31) ----
        if (tid < 32) {
            float4 s = gatebuf[t & 1][0][tid];
            #pragma unroll
            for (int w8 = 1; w8 < 8; w8++) {
                float4 v = gatebuf[t & 1][w8][tid];
                s.x += v.x; s.y += v.y; s.z += v.z; s.w += v.w;
            }
            float si = fast_sig(s.x + bb[0]);
            float sf = fast_sig(s.y + bb[1]);
            float gg = fast_tanh(s.z + bb[2]);
            float so = fast_sig(s.w + bb[3]);
            c_state = sf * c_state + si * gg;
            float hv = so * fast_tanh(c_state);
            unsigned long long word =
                ((unsigned long long)(unsigned)(t + 1) << 32) | (unsigned long long)__float_as_uint(hv);
            __hip_atomic_store(h_own + (size_t)(t + 1) * HID + g * 32 + tid, word,
                               __ATOMIC_RELAXED, __HIP_MEMORY_SCOPE_AGENT);
            if (layer == 2) h2f[(size_t)t * HID + g * 32 + tid] = hv;
        }
        // gatebuf WAR across steps is safe: writers of parity p at step t+2 have
        // passed barrier(t+1), which wave 0 reaches only after reading parity p at
        // step t. No second barrier needed; tag rides in the publish word.
    }
}

// ---------------- K3: logits = h2 @ w_lin^T + b_lin (tiled fp32 GEMM) ----------------
#define BM 64
#define BN 64
#define BK 32
__global__ __launch_bounds__(256) void k3_logits(
    const float* __restrict__ A, const float* __restrict__ w_lin,
    const float* __restrict__ b_lin, float* __restrict__ out)
{
    int m0 = blockIdx.x * BM;
    int n0 = blockIdx.y * BN;
    int tid = threadIdx.x;
    __shared__ float As[BM][BK + 1];
    __shared__ float Bs[BN][BK + 1];
    float accv[4][4] = {};
    int tx = tid % 16, ty = tid / 16;

    for (int k0 = 0; k0 < HID; k0 += BK) {
        int row = tid / 4;
        int kq  = (tid % 4) * 8;
        {
            const float4* src = (const float4*)(A + (m0 + row) * HID + k0 + kq);
            float4 v0 = src[0], v1 = src[1];
            As[row][kq + 0] = v0.x; As[row][kq + 1] = v0.y; As[row][kq + 2] = v0.z; As[row][kq + 3] = v0.w;
            As[row][kq + 4] = v1.x; As[row][kq + 5] = v1.y; As[row][kq + 6] = v1.z; As[row][kq + 7] = v1.w;
        }
        {
            int n = n0 + row;
            float4 v0 = make_float4(0.f, 0.f, 0.f, 0.f), v1 = v0;
            if (n < NSPK) {
                const float4* src = (const float4*)(w_lin + n * HID + k0 + kq);
                v0 = src[0]; v1 = src[1];
            }
            Bs[row][kq + 0] = v0.x; Bs[row][kq + 1] = v0.y; Bs[row][kq + 2] = v0.z; Bs[row][kq + 3] = v0.w;
            Bs[row][kq + 4] = v1.x; Bs[row][kq + 5] = v1.y; Bs[row][kq + 6] = v1.z; Bs[row][kq + 7] = v1.w;
        }
        __syncthreads();
        #pragma unroll
        for (int kk = 0; kk < BK; kk++) {
            float a0 = As[ty * 4 + 0][kk], a1 = As[ty * 4 + 1][kk];
            float a2 = As[ty * 4 + 2][kk], a3 = As[ty * 4 + 3][kk];
            float b0 = Bs[tx * 4 + 0][kk], b1 = Bs[tx * 4 + 1][kk];
            float b2 = Bs[tx * 4 + 2][kk], b3 = Bs[tx * 4 + 3][kk];
            accv[0][0] += a0 * b0; accv[0][1] += a0 * b1; accv[0][2] += a0 * b2; accv[0][3] += a0 * b3;
            accv[1][0] += a1 * b0; accv[1][1] += a1 * b1; accv[1][2] += a1 * b2; accv[1][3] += a1 * b3;
            accv[2][0] += a2 * b0; accv[2][1] += a2 * b1; accv[2][2] += a2 * b2; accv[2][3] += a2 * b3;
            accv[3][0] += a3 * b0; accv[3][1] += a3 * b1; accv[3][2] += a3 * b2; accv[3][3] += a3 * b3;
        }
        __syncthreads();
    }
    #pragma unroll
    for (int i = 0; i < 4; i++) {
        int m = m0 + ty * 4 + i;
        #pragma unroll
        for (int j = 0; j < 4; j++) {
            int n = n0 + tx * 4 + j;
            if (n < NSPK) out[(size_t)m * NSPK + n] = accv[i][j] + b_lin[n];
        }
    }
}

// ---------------- K4: in-place row-wise log_softmax over NSPK ----------------
__global__ __launch_bounds__(256) void k4_logsoftmax(float* __restrict__ out)
{
    int t = blockIdx.x;
    float* row = out + (size_t)t * NSPK;
    int tid = threadIdx.x;
    __shared__ float red[8];
    float vals[5];
    float lmax = -1e30f;
    #pragma unroll
    for (int k = 0; k < 5; k++) {
        int n = tid + k * 256;
        vals[k] = (n < NSPK) ? row[n] : -1e30f;
        lmax = fmaxf(lmax, vals[k]);
    }
    #pragma unroll
    for (int m = 1; m < 64; m <<= 1) lmax = fmaxf(lmax, __shfl_xor(lmax, m, 64));
    int wave = tid >> 6;
    if ((tid & 63) == 0) red[wave] = lmax;
    __syncthreads();
    float gmax = fmaxf(fmaxf(red[0], red[1]), fmaxf(red[2], red[3]));
    float lsum = 0.f;
    #pragma unroll
    for (int k = 0; k < 5; k++) {
        int n = tid + k * 256;
        if (n < NSPK) lsum += __expf(vals[k] - gmax);
    }
    #pragma unroll
    for (int m = 1; m < 64; m <<= 1) lsum += __shfl_xor(lsum, m, 64);
    if ((tid & 63) == 0) red[4 + wave] = lsum;
    __syncthreads();
    float lse = logf(red[4] + red[5] + red[6] + red[7]) + gmax;
    #pragma unroll
    for (int k = 0; k < 5; k++) {
        int n = tid + k * 256;
        if (n < NSPK) row[n] = vals[k] - lse;
    }
}

extern "C" void kernel_launch(void* const* d_in, const int* in_sizes, int n_in,
                              void* d_out, int out_size, void* d_ws, size_t ws_size,
                              hipStream_t stream) {
    const float* x     = (const float*)d_in[0];
    const float* w_ih0 = (const float*)d_in[1];
    const float* w_hh0 = (const float*)d_in[2];
    const float* b_ih0 = (const float*)d_in[3];
    const float* b_hh0 = (const float*)d_in[4];
    const float* w_ih1 = (const float*)d_in[5];
    const float* w_hh1 = (const float*)d_in[6];
    const float* b_ih1 = (const float*)d_in[7];
    const float* b_hh1 = (const float*)d_in[8];
    const float* w_ih2 = (const float*)d_in[9];
    const float* w_hh2 = (const float*)d_in[10];
    const float* b_ih2 = (const float*)d_in[11];
    const float* b_hh2 = (const float*)d_in[12];
    const float* w_lin = (const float*)d_in[13];
    const float* b_lin = (const float*)d_in[14];

    unsigned long long* hbuf = (unsigned long long*)d_ws;
    float* h2f = (float*)((char*)d_ws + H2F_OFF_BYTES);
    float* out = (float*)d_out;

    k0_init<<<1, 1024, 0, stream>>>(hbuf);
    k2_lstm<<<NBLOCKS, K2_THREADS, 0, stream>>>(
        x, w_ih0, w_hh0, b_ih0, b_hh0,
        w_ih1, w_hh1, b_ih1, b_hh1,
        w_ih2, w_hh2, b_ih2, b_hh2,
        hbuf, h2f);
    k3_logits<<<dim3(16, 20), 256, 0, stream>>>(h2f, w_lin, b_lin, out);
    k4_logsoftmax<<<T_STEPS, 256, 0, stream>>>(out);
}